// Round 15
// baseline (70230.078 us; speedup 1.0000x reference)
//
#include <hip/hip_runtime.h>
#include <stdint.h>
#include <stddef.h>

#define T_STEPS 512
#define B_SZ    128
#define DIN     1024
#define H_SZ    2048
#define NG      8192            // 4*H
#define BH      (B_SZ * H_SZ)   // 262144

typedef __attribute__((ext_vector_type(8))) short bf16x8;
typedef __attribute__((ext_vector_type(16))) float f32x16;

static __device__ __forceinline__ unsigned short f2bf(float x) {
  unsigned int u = __float_as_uint(x);
  u += 0x7fffu + ((u >> 16) & 1u);   // RNE; inputs finite
  return (unsigned short)(u >> 16);
}

static __device__ __forceinline__ float sigm(float x) {
  return 1.0f / (1.0f + __expf(-x));
}
static __device__ __forceinline__ float tanh_(float x) {
  float e = __expf(-2.0f * fabsf(x));  // in (0,1], no overflow
  float t = (1.0f - e) / (1.0f + e);
  return x < 0.0f ? -t : t;
}

// global -> LDS async copy, 16B per lane (wave-uniform LDS base).
static __device__ __forceinline__ void async_load16(const void* gsrc, void* ldst) {
  __builtin_amdgcn_global_load_lds(
      (__attribute__((address_space(1))) void*)(const_cast<void*>(gsrc)),
      (__attribute__((address_space(3))) void*)ldst,
      16, 0, 0);
}

// Barrier that memory ops cannot be compiler-moved across (rd4's NaN fix).
static __device__ __forceinline__ void wg_barrier_pinned() {
  __builtin_amdgcn_s_barrier();
  asm volatile("" ::: "memory");
  __builtin_amdgcn_sched_barrier(0);
}

// ---- flag protocol (agent scope, cross-XCD; rd13-validated mechanics) ----
static __device__ __forceinline__ void publish(unsigned* flag, unsigned epoch) {
  __syncthreads();                       // drain WG stores
  if (threadIdx.x == 0) {
    __threadfence();                     // agent release fence (L2 writeback)
    __hip_atomic_store(flag, epoch, __ATOMIC_RELEASE, __HIP_MEMORY_SCOPE_AGENT);
  }
}
static __device__ __forceinline__ void await(const unsigned* flag, unsigned epoch) {
  if (threadIdx.x == 0)
    while (__hip_atomic_load(flag, __ATOMIC_ACQUIRE, __HIP_MEMORY_SCOPE_AGENT) < epoch)
      __builtin_amdgcn_s_sleep(8);
  __syncthreads();
}
static __device__ __forceinline__ void await_ge(const unsigned* p, unsigned tgt) {
  if (threadIdx.x == 0)
    while (__hip_atomic_load(p, __ATOMIC_ACQUIRE, __HIP_MEMORY_SCOPE_AGENT) < tgt)
      __builtin_amdgcn_s_sleep(32);
  __syncthreads();
}
// Read-certification post (syncthreads drains the WG's loads first).
static __device__ __forceinline__ void post_cnt(unsigned* p) {
  __syncthreads();
  if (threadIdx.x == 0)
    __hip_atomic_fetch_add(p, 1u, __ATOMIC_RELEASE, __HIP_MEMORY_SCOPE_AGENT);
}
// Data-certification post (h-state written): fence then count.
static __device__ __forceinline__ void post_data(unsigned* p) {
  __syncthreads();
  if (threadIdx.x == 0) {
    __threadfence();                     // agent release fence
    __hip_atomic_fetch_add(p, 1u, __ATOMIC_RELEASE, __HIP_MEMORY_SCOPE_AGENT);
  }
}

__global__ void cvt_x_bf16(const float4* __restrict__ in, ushort4* __restrict__ out, int n4) {
  int i = blockIdx.x * blockDim.x + threadIdx.x;
  int st = gridDim.x * blockDim.x;
  for (; i < n4; i += st) {
    float4 v = in[i];
    ushort4 o;
    o.x = f2bf(v.x); o.y = f2bf(v.y); o.z = f2bf(v.z); o.w = f2bf(v.w);
    out[i] = o;
  }
}

__global__ void build_wcat(const float* __restrict__ wa, const float* __restrict__ wb,
                           unsigned short* __restrict__ outw, int ka, int K) {
  int k = blockIdx.x * blockDim.x + threadIdx.x;
  int n = blockIdx.y;
  if (k >= K) return;
  int kb = K - ka;
  float v = (k < ka) ? wa[(size_t)n * ka + k]
                     : wb[(size_t)n * kb + (k - ka)];
  outw[(size_t)n * K + k] = f2bf(v);
}

// flags layout: [0,64) f1 | [64,128) f0 | [128,256) edge banks |
// 256 h0cnt | 257 h1cnt | 258,259 h0rd2[2] | 260,261 h1rd2[2]
__global__ void init_state(const float* __restrict__ h0, const float* __restrict__ c0,
                           unsigned short* __restrict__ hb0, unsigned short* __restrict__ hb1,
                           float* __restrict__ cws, unsigned* __restrict__ flags) {
  int i = blockIdx.x * blockDim.x + threadIdx.x;
  if (i < 262) flags[i] = (i == 256 || i == 257) ? 64u : 0u;
  if (i < BH) {
    hb0[i] = f2bf(h0[i]);
    hb1[i] = f2bf(h0[BH + i]);
    cws[i] = c0[i];
    cws[BH + i] = c0[BH + i];
  }
}

// K-range GEMM, 32x32x16 MFMA (rd12/13-verified). Partial over k in
// [kofs, kofs+KT*64) of gates[*,128-tile] = A[128,K]@Wcat^T. 4 waves.
template<int KT>
static __device__ __forceinline__ void gemm_ks(
    unsigned short (*Bbuf)[128 * 64],
    const unsigned short* __restrict__ a0, int s0, int ksplit,
    const unsigned short* __restrict__ a1,          // row stride H_SZ
    int kofs,
    const unsigned short* __restrict__ w, int wstr, // [NG][wstr] bf16
    int tid, int lane, int wv, int n0h,
    f32x16 (&acc)[4])
{
  const int arow = wv * 32 + (lane & 31);
  const unsigned short* r0p = a0 + (size_t)arow * s0;
  const unsigned short* r1p = a1 + (size_t)arow * H_SZ;
  const int khi = (lane >> 5) << 3;   // k half-offset: 0 or 8 elems

  auto loadA = [&](int kt, bf16x8 (&A)[4]) {
    const int kbg = kofs + (kt << 6);
    const bool sA = kbg < ksplit;     // 64-tiles never straddle
    const unsigned short* bp = (sA ? r0p + kbg : r1p + (kbg - ksplit)) + khi;
#pragma unroll
    for (int cc = 0; cc < 4; ++cc)
      A[cc] = *(const bf16x8*)(bp + cc * 16);
  };

  auto stageB = [&](int kt) {
    const int kbg = kofs + (kt << 6);
#pragma unroll
    for (int it = 0; it < 4; ++it) {
      int cid = it * 256 + tid;
      int nl  = cid >> 3;                            // gate-row 0..127
      int chs = (cid & 7) ^ (nl & 7);                // pre-swizzled source chunk
      int nn  = ((nl >> 5) << 11) + n0h + (nl & 31);
      const unsigned short* src = w + (size_t)nn * wstr + kbg + (chs << 3);
      async_load16(src, &Bbuf[kt & 3][(it * 256 + wv * 64) * 8]);
    }
  };

  auto iter = [&](int kt, bf16x8 (&A)[4]) {
    if (kt + 3 < KT) stageB(kt + 3);
    const int bq = kt & 3;
#pragma unroll
    for (int cc = 0; cc < 4; ++cc) {
      const int chunk = (((cc << 1) + (lane >> 5)) ^ (lane & 7)) << 3;
      bf16x8 bfr[4];
#pragma unroll
      for (int ct = 0; ct < 4; ++ct)
        bfr[ct] = *(const bf16x8*)&Bbuf[bq][(ct * 32 + (lane & 31)) * 64 + chunk];
#pragma unroll
      for (int ct = 0; ct < 4; ++ct)
        acc[ct] = __builtin_amdgcn_mfma_f32_32x32x16_bf16(A[cc], bfr[ct], acc[ct], 0, 0, 0);
    }
    if (kt + 4 < KT) loadA(kt + 4, A);
    int rem = KT - 1 - kt;
    if (rem >= 4)      asm volatile("s_waitcnt vmcnt(20)" ::: "memory");
    else if (rem == 3) asm volatile("s_waitcnt vmcnt(16)" ::: "memory");
    else if (rem == 2) asm volatile("s_waitcnt vmcnt(8)"  ::: "memory");
    else if (rem == 1) asm volatile("s_waitcnt vmcnt(0)"  ::: "memory");
    if (rem > 0) wg_barrier_pinned();
  };

  asm volatile("s_waitcnt vmcnt(0)" ::: "memory");   // entry guard

  bf16x8 A0[4], A1[4], A2[4], A3[4];
  stageB(0); loadA(0, A0);
  stageB(1); loadA(1, A1);
  stageB(2); loadA(2, A2);
  loadA(3, A3);
  asm volatile("s_waitcnt vmcnt(24)" ::: "memory");  // retire B0
  wg_barrier_pinned();

  for (int kt = 0; kt < KT; kt += 4) {
    iter(kt,     A0);
    iter(kt + 1, A1);
    iter(kt + 2, A2);
    iter(kt + 3, A3);
  }
}

static __device__ __forceinline__ void store_partial(
    const f32x16 (&acc)[4], float* __restrict__ p, int lane, int wv) {
  const int col = lane & 31;
  const int rbase = wv * 32 + ((lane >> 5) << 2);
#pragma unroll
  for (int ct = 0; ct < 4; ++ct)
#pragma unroll
    for (int reg = 0; reg < 16; ++reg) {
      int row = rbase + (reg & 3) + ((reg >> 2) << 3);
      p[((ct << 7) + row) * 32 + col] = acc[ct][reg];
    }
}
static __device__ __forceinline__ void combine_add(
    f32x16 (&acc)[4], const float* __restrict__ p, int lane, int wv) {
  const int col = lane & 31;
  const int rbase = wv * 32 + ((lane >> 5) << 2);
#pragma unroll
  for (int ct = 0; ct < 4; ++ct)
#pragma unroll
    for (int reg = 0; reg < 16; ++reg) {
      int row = rbase + (reg & 3) + ((reg >> 2) << 3);
      acc[ct][reg] += p[((ct << 7) + row) * 32 + col];
    }
}

static __device__ __forceinline__ void lstm_epilogue(
    const f32x16 (&acc)[4], const float* __restrict__ bias,
    float* __restrict__ c, unsigned short* __restrict__ hout,
    float* __restrict__ fout, int lane, int wv, int n0h) {
  const int hc = n0h + (lane & 31);
  const float bi  = bias[hc];
  const float bff = bias[H_SZ + hc];
  const float bg  = bias[2 * H_SZ + hc];
  const float bo  = bias[3 * H_SZ + hc];
  const int rbase = wv * 32 + ((lane >> 5) << 2);
#pragma unroll
  for (int reg = 0; reg < 16; ++reg) {
    int row = rbase + (reg & 3) + ((reg >> 2) << 3);
    size_t idx = (size_t)row * H_SZ + hc;
    float iv = sigm(acc[0][reg] + bi);
    float fv = sigm(acc[1][reg] + bff);
    float gv = tanh_(acc[2][reg] + bg);
    float ov = sigm(acc[3][reg] + bo);
    float cn = fv * c[idx] + iv * gv;
    c[idx] = cn;
    float hn = ov * tanh_(cn);
    hout[idx] = f2bf(hn);
    if (fout) fout[idx] = hn;
  }
}

// Fused G step-pairs: grid 256 = 4 roles x 64 cb, all WGs co-resident (1/CU).
// Step t: roles 0/1 = L1(t) k-halves; roles 2/3 = L0(t+1) k-halves.
// Actual operand reads: role 0 -> h0cur only; role 1 -> hb1[t&1] only;
// roles 2,3 -> x(t+1) + h0cur.
// Sync: h0cnt/h1cnt = data-ready (64 posts/step each); parity read-counters
// h0rd2[slot]/h1rd2[slot] = overwrite safety. Readers of slot s post to
// counter[s]; same-step readers always touch the OTHER slot, so a writer's
// await on counter[s'] cannot be polluted by same-step posts (rd14's race).
// Targets: floor((t+1)/2) prior reader-steps x 192 (h0: roles 0,2,3) or
// x 64 (h1: role 1). f1/f0 per-cb flags certify k-high partials.
template<int KT1, int KT0>
__global__ __launch_bounds__(256) void lstm_fused(
    const unsigned short* __restrict__ xbf,
    const unsigned short* __restrict__ Wc1, const float* __restrict__ b1,
    const unsigned short* __restrict__ Wc0, const float* __restrict__ b0,
    unsigned short* __restrict__ hb0, unsigned short* __restrict__ hb1,
    float* __restrict__ c1buf, float* __restrict__ c0buf,
    float* __restrict__ p1, float* __restrict__ p0,
    unsigned* __restrict__ flg, int tbase, int G)
{
  __shared__ __align__(16) unsigned short Bbuf[4][128 * 64];   // 64 KB
  const int tid = threadIdx.x, lane = tid & 63, wv = tid >> 6;
  const int role = blockIdx.x >> 6, cb = blockIdx.x & 63, n0h = cb << 5;
  unsigned* f1    = flg;
  unsigned* f0    = flg + 64;
  unsigned* h0cnt = flg + 256;
  unsigned* h1cnt = flg + 257;
  unsigned* h0rd2 = flg + 258;   // [2]
  unsigned* h1rd2 = flg + 260;   // [2]

  for (int g = 0; g < G; ++g) {
    const int t = tbase + g;
    const unsigned short* h0cur = hb0 + (size_t)((t + 1) & 1) * BH;
    const unsigned prior = (unsigned)((t + 1) >> 1);   // reader-steps before t
    f32x16 acc[4] = {};

    if (role == 0) {
      await_ge(h0cnt, 64u * (t + 1));
      gemm_ks<KT1>(Bbuf, h0cur, H_SZ, 2048, hb1 + (size_t)(t & 1) * BH, 0,
                   Wc1, 4096, tid, lane, wv, n0h, acc);
      post_cnt(h0rd2 + ((t + 1) & 1));
      await(f1 + cb, (unsigned)(t + 1));
      combine_add(acc, p1 + (size_t)cb * 16384, lane, wv);
      await_ge(h1rd2 + ((t + 1) & 1), 64u * prior);    // old readers of target slot
      lstm_epilogue(acc, b1, c1buf, hb1 + (size_t)((t + 1) & 1) * BH,
                    nullptr, lane, wv, n0h);
      post_data(h1cnt);
    } else if (role == 1) {
      await_ge(h1cnt, 64u * (t + 1));
      gemm_ks<KT1>(Bbuf, h0cur, H_SZ, 2048, hb1 + (size_t)(t & 1) * BH, 2048,
                   Wc1, 4096, tid, lane, wv, n0h, acc);
      post_cnt(h1rd2 + (t & 1));
      store_partial(acc, p1 + (size_t)cb * 16384, lane, wv);
      publish(f1 + cb, (unsigned)(t + 1));
    } else if (role == 2) {
      await_ge(h0cnt, 64u * (t + 1));
      gemm_ks<KT0>(Bbuf, xbf + (size_t)(t + 1) * B_SZ * DIN, DIN, 1024, h0cur, 0,
                   Wc0, 3072, tid, lane, wv, n0h, acc);
      post_cnt(h0rd2 + ((t + 1) & 1));
      await(f0 + cb, (unsigned)(t + 1));
      combine_add(acc, p0 + (size_t)cb * 16384, lane, wv);
      await_ge(h0rd2 + (t & 1), 192u * prior);         // old readers of target slot
      lstm_epilogue(acc, b0, c0buf, hb0 + (size_t)(t & 1) * BH,
                    nullptr, lane, wv, n0h);
      post_data(h0cnt);
    } else {
      await_ge(h0cnt, 64u * (t + 1));
      gemm_ks<KT0>(Bbuf, xbf + (size_t)(t + 1) * B_SZ * DIN, DIN, 1024, h0cur, 1536,
                   Wc0, 3072, tid, lane, wv, n0h, acc);
      post_cnt(h0rd2 + ((t + 1) & 1));
      store_partial(acc, p0 + (size_t)cb * 16384, lane, wv);
      publish(f0 + cb, (unsigned)(t + 1));
    }
  }
}

// Single layer, K-split (schedule edges, rd13-validated): grid 128.
template<int KT>
__global__ __launch_bounds__(256) void lstm_solo_ks(
    const unsigned short* __restrict__ a0, int s0, int ksplit,
    const unsigned short* __restrict__ a1,
    int kofs1,
    const unsigned short* __restrict__ w, int wstr, const float* __restrict__ bias,
    float* __restrict__ c, unsigned short* __restrict__ hout, float* __restrict__ fout,
    float* __restrict__ part, unsigned* __restrict__ flg, unsigned epoch)
{
  __shared__ __align__(16) unsigned short Bbuf[4][128 * 64];   // 64 KB
  const int tid = threadIdx.x, lane = tid & 63, wv = tid >> 6;
  const int half = blockIdx.x >> 6, cb = blockIdx.x & 63, n0h = cb << 5;
  f32x16 acc[4] = {};

  if (half == 0) {
    gemm_ks<KT>(Bbuf, a0, s0, ksplit, a1, 0, w, wstr, tid, lane, wv, n0h, acc);
    await(flg + cb, epoch);
    combine_add(acc, part + (size_t)cb * 16384, lane, wv);
    lstm_epilogue(acc, bias, c, hout, fout, lane, wv, n0h);
  } else {
    gemm_ks<KT>(Bbuf, a0, s0, ksplit, a1, kofs1, w, wstr, tid, lane, wv, n0h, acc);
    store_partial(acc, part + (size_t)cb * 16384, lane, wv);
    publish(flg + cb, epoch);
  }
}

extern "C" void kernel_launch(void* const* d_in, const int* in_sizes, int n_in,
                              void* d_out, int out_size, void* d_ws, size_t ws_size,
                              hipStream_t stream) {
  (void)in_sizes; (void)n_in; (void)out_size; (void)ws_size;
  const float* x    = (const float*)d_in[0];
  const float* h0   = (const float*)d_in[1];
  const float* c0   = (const float*)d_in[2];
  const float* Wih0 = (const float*)d_in[3];
  const float* Whh0 = (const float*)d_in[4];
  const float* b0   = (const float*)d_in[5];
  const float* Wih1 = (const float*)d_in[6];
  const float* Whh1 = (const float*)d_in[7];
  const float* b1   = (const float*)d_in[8];
  float* out = (float*)d_out;

  unsigned short* xbf = (unsigned short*)d_ws;                     // 134 MB
  unsigned short* Wc0 = xbf + (size_t)T_STEPS * B_SZ * DIN;        // 50 MB
  unsigned short* Wc1 = Wc0 + (size_t)NG * 3072;                   // 67 MB
  unsigned short* hb0 = Wc1 + (size_t)NG * 4096;                   // 2*BH
  unsigned short* hb1 = hb0 + 2 * (size_t)BH;                      // 2*BH
  float*          cws = (float*)(hb1 + 2 * (size_t)BH);            // 2*BH fp32
  float*          p1  = cws + 2 * (size_t)BH;                      // 4MB
  float*          p0  = p1 + 64 * 16384;                           // 4MB
  unsigned*       flg = (unsigned*)(p0 + 64 * 16384);              // 262 u32
  unsigned* flagsE = flg + 128;    // edge banks (2 x 64)

  cvt_x_bf16<<<dim3(4096), dim3(256), 0, stream>>>(
      (const float4*)x, (ushort4*)xbf, T_STEPS * B_SZ * DIN / 4);
  build_wcat<<<dim3(12, NG), dim3(256), 0, stream>>>(Wih0, Whh0, Wc0, DIN, 3072);
  build_wcat<<<dim3(16, NG), dim3(256), 0, stream>>>(Wih1, Whh1, Wc1, H_SZ, 4096);
  init_state<<<dim3(BH / 256), dim3(256), 0, stream>>>(h0, c0, hb0, hb1, cws, flg);

  // L0(0): writes h0 state 0 -> hb0 slot 1 (certified to fused via stream order).
  lstm_solo_ks<24><<<dim3(128), dim3(256), 0, stream>>>(
      xbf, DIN, 1024, hb0 + 0, 1536, Wc0, 3072, b0,
      cws, hb0 + BH, nullptr, p0, flagsE, 1u);

  // Fused pairs t = 0..510 (L1(t) + L0(t+1)) in G-step chunks.
  int t = 0;
  while (t < T_STEPS - 1) {
    int G = (T_STEPS - 1 - t < 16) ? (T_STEPS - 1 - t) : 16;
    lstm_fused<32, 24><<<dim3(256), dim3(256), 0, stream>>>(
        xbf, Wc1, b1, Wc0, b0, hb0, hb1,
        cws + BH, cws, p1, p0, flg, t, G);
    t += G;
  }

  // L1(511): reads hb0 slot0 (state 511), hb1 slot1 (state 510); writes out.
  lstm_solo_ks<32><<<dim3(128), dim3(256), 0, stream>>>(
      hb0 + 0, H_SZ, 2048, hb1 + BH, 2048, Wc1, 4096, b1,
      cws + BH, hb1 + 0, out, p1, flagsE + 64, 1u);
}

// Round 16
// 38145.901 us; speedup vs baseline: 1.8411x; 1.8411x over previous
//
#include <hip/hip_runtime.h>
#include <stdint.h>
#include <stddef.h>

#define T_STEPS 512
#define B_SZ    128
#define DIN     1024
#define H_SZ    2048
#define NG      8192            // 4*H
#define BH      (B_SZ * H_SZ)   // 262144

typedef __attribute__((ext_vector_type(8))) short bf16x8;
typedef __attribute__((ext_vector_type(4))) float f32x4;

static __device__ __forceinline__ unsigned short f2bf(float x) {
  unsigned int u = __float_as_uint(x);
  u += 0x7fffu + ((u >> 16) & 1u);   // RNE; inputs finite
  return (unsigned short)(u >> 16);
}

static __device__ __forceinline__ float sigm(float x) {
  return 1.0f / (1.0f + __expf(-x));
}
static __device__ __forceinline__ float tanh_(float x) {
  float e = __expf(-2.0f * fabsf(x));  // in (0,1], no overflow
  float t = (1.0f - e) / (1.0f + e);
  return x < 0.0f ? -t : t;
}

// global -> LDS async copy, 16B per lane (wave-uniform LDS base).
static __device__ __forceinline__ void async_load16(const void* gsrc, void* ldst) {
  __builtin_amdgcn_global_load_lds(
      (__attribute__((address_space(1))) void*)(const_cast<void*>(gsrc)),
      (__attribute__((address_space(3))) void*)ldst,
      16, 0, 0);
}

// Barrier that memory ops cannot be compiler-moved across (rd4's NaN fix).
static __device__ __forceinline__ void wg_barrier_pinned() {
  __builtin_amdgcn_s_barrier();
  asm volatile("" ::: "memory");
  __builtin_amdgcn_sched_barrier(0);
}

// Release-publish: WG's stores drained, agent fence, single release STORE
// (no RMW anywhere in the protocol — rd15's counter contention is the lesson).
static __device__ __forceinline__ void publish(unsigned* flag, unsigned v) {
  __syncthreads();
  if (threadIdx.x == 0) {
    __threadfence();                     // agent-scope release
    __hip_atomic_store(flag, v, __ATOMIC_RELEASE, __HIP_MEMORY_SCOPE_AGENT);
  }
}

__global__ void cvt_x_bf16(const float4* __restrict__ in, ushort4* __restrict__ out, int n4) {
  int i = blockIdx.x * blockDim.x + threadIdx.x;
  int st = gridDim.x * blockDim.x;
  for (; i < n4; i += st) {
    float4 v = in[i];
    ushort4 o;
    o.x = f2bf(v.x); o.y = f2bf(v.y); o.z = f2bf(v.z); o.w = f2bf(v.w);
    out[i] = o;
  }
}

__global__ void build_wcat(const float* __restrict__ wa, const float* __restrict__ wb,
                           unsigned short* __restrict__ outw, int ka, int K) {
  int k = blockIdx.x * blockDim.x + threadIdx.x;
  int n = blockIdx.y;
  if (k >= K) return;
  int kb = K - ka;
  float v = (k < ka) ? wa[(size_t)n * ka + k]
                     : wb[(size_t)n * kb + (k - ka)];
  outw[(size_t)n * K + k] = f2bf(v);
}

// flags: f0[128] then f1[128], each padded to 16 u32 (64B line). 4096 u32.
__global__ void init_state(const float* __restrict__ h0, const float* __restrict__ c0,
                           unsigned short* __restrict__ hb0, unsigned short* __restrict__ hb1,
                           float* __restrict__ cws, unsigned* __restrict__ flags) {
  int i = blockIdx.x * blockDim.x + threadIdx.x;
  if (i < 4096) flags[i] = 0u;
  if (i < BH) {
    hb0[i] = f2bf(h0[i]);
    hb1[i] = f2bf(h0[BH + i]);
    cws[i] = c0[i];
    cws[BH + i] = c0[BH + i];
  }
}

// One LSTM cell step (rd10-verified, 19.9ms body — copied verbatim).
// WG tile = 64 rows x 128 gate-cols (32 h-cols). Within a layer: 128 WGs =
// 2 row-blocks (mb) x 64 col-blocks (cb). Wave wv owns rows mb*64+wv*16..+16.
// Lane holds all 4 gates: acc[ct], ct = gate*2 + p -> lane-local epilogue.
// A: direct global->register, 4 named sets, 4-ahead.
// B: LDS ring 4 x 16KB, staged 3 ahead via global_load_lds, XOR-swizzled.
// Per-wave VMEM per iter: 4 stageB chunks + 2 loadA.
template<int K, int KSPLIT>
static __device__ __forceinline__ void lstm_step_body(
    unsigned short (*Bbuf)[128 * 64],
    const unsigned short* __restrict__ a0,   // [128][KSPLIT] row-major
    const unsigned short* __restrict__ a1,   // [128][H_SZ] row-major
    const unsigned short* __restrict__ w,    // [NG][K] bf16
    const float* __restrict__ bias,          // [NG] fp32
    float* __restrict__ c,                   // [B][H] fp32, in-place (tile-private)
    unsigned short* __restrict__ hout,       // [B][H] bf16
    float* __restrict__ fout,                // optional [B][H] fp32
    int tid, int lane, int wv, int mb, int n0h)
{
  constexpr int KT = K >> 6;   // 48 or 64, divisible by 4
  f32x4 acc[8] = {};

  const int arow = mb * 64 + wv * 16 + (lane & 15);
  const unsigned short* r0p = a0 + (size_t)arow * KSPLIT;
  const unsigned short* r1p = a1 + (size_t)arow * H_SZ;
  const int klo = (lane >> 4) << 3;   // lane-group k offset (elems)

  auto loadA = [&](int kt, bf16x8 (&A)[2]) {
    const int kb = kt << 6;
    const bool sA = kb < KSPLIT;     // tiles never straddle (KSPLIT % 64 == 0)
    const unsigned short* bp = (sA ? r0p : r1p) + (sA ? kb : kb - KSPLIT) + klo;
    A[0] = *(const bf16x8*)(bp);
    A[1] = *(const bf16x8*)(bp + 32);
  };

  // B-tile 128 gate-rows x 64 k = 16KB = 1024 x 16B chunks; 4 per thread.
  auto stageB = [&](int kt) {
    const int kb = kt << 6;
#pragma unroll
    for (int it = 0; it < 4; ++it) {
      int cid = it * 256 + tid;
      int nl  = cid >> 3;                            // gate-row 0..127
      int chs = (cid & 7) ^ (nl & 7);                // pre-swizzled source chunk
      int nn  = ((nl >> 5) << 11) + n0h + (nl & 31);
      const unsigned short* src = w + (size_t)nn * K + kb + (chs << 3);
      async_load16(src, &Bbuf[kt & 3][(it * 256 + wv * 64) * 8]);
    }
  };

  auto iter = [&](int kt, bf16x8 (&A)[2]) {
    if (kt + 3 < KT) stageB(kt + 3);                 // issue stage early
    const int bq = kt & 3;
#pragma unroll
    for (int kkk = 0; kkk < 2; ++kkk) {
      const int ch = kkk * 4 + (lane >> 4);
      const int cswz = (ch ^ (lane & 7)) << 3;       // (nl&7) == lane&7 for all ct
      bf16x8 bfr[8];
#pragma unroll
      for (int ct = 0; ct < 8; ++ct)
        bfr[ct] = *(const bf16x8*)&Bbuf[bq][(ct * 16 + (lane & 15)) * 64 + cswz];
#pragma unroll
      for (int ct = 0; ct < 8; ++ct)
        acc[ct] = __builtin_amdgcn_mfma_f32_16x16x32_bf16(A[kkk], bfr[ct], acc[ct], 0, 0, 0);
    }
    if (kt + 4 < KT) loadA(kt + 4, A);               // refill own named set post-use
    int rem = KT - 1 - kt;
    if (rem >= 4)      asm volatile("s_waitcnt vmcnt(14)" ::: "memory");
    else if (rem == 3) asm volatile("s_waitcnt vmcnt(12)" ::: "memory");
    else if (rem == 2) asm volatile("s_waitcnt vmcnt(6)"  ::: "memory");
    else if (rem == 1) asm volatile("s_waitcnt vmcnt(0)"  ::: "memory");
    wg_barrier_pinned();
  };

  // Entry guard: prologue counts assume an empty vmcnt FIFO.
  asm volatile("s_waitcnt vmcnt(0)" ::: "memory");

  bf16x8 A0[2], A1[2], A2[2], A3[2];
  // Prologue queue: B0x4,A0x2,B1x4,A1x2,B2x4,A2x2,A3x2 = 20 ops; retire B0 -> 16.
  stageB(0); loadA(0, A0);
  stageB(1); loadA(1, A1);
  stageB(2); loadA(2, A2);
  loadA(3, A3);
  asm volatile("s_waitcnt vmcnt(16)" ::: "memory");
  wg_barrier_pinned();

  for (int kt = 0; kt < KT; kt += 4) {
    iter(kt,     A0);
    iter(kt + 1, A1);
    iter(kt + 2, A2);
    iter(kt + 3, A3);
  }

  // Epilogue (lane-local). C/D map: col(nl)=lane&15 -> nl = ct*16+(lane&15);
  // gate = ct>>1; hcol = n0h + (ct&1)*16 + (lane&15).
#pragma unroll
  for (int p = 0; p < 2; ++p) {
    const int hc = n0h + p * 16 + (lane & 15);
    const float bi  = bias[hc];
    const float bff = bias[H_SZ + hc];
    const float bg  = bias[2 * H_SZ + hc];
    const float bo  = bias[3 * H_SZ + hc];
#pragma unroll
    for (int r = 0; r < 4; ++r) {
      int row = mb * 64 + wv * 16 + ((lane >> 4) << 2) + r;
      size_t idx = (size_t)row * H_SZ + hc;
      float iv = sigm(acc[p    ][r] + bi);
      float fv = sigm(acc[p + 2][r] + bff);
      float gv = tanh_(acc[p + 4][r] + bg);
      float ov = sigm(acc[p + 6][r] + bo);
      float cn = fv * c[idx] + iv * gv;
      c[idx] = cn;
      float hn = ov * tanh_(cn);
      hout[idx] = f2bf(hn);
      if (fout) fout[idx] = hn;
    }
  }
}

// Single step (schedule edges). Grid 128 = 2 mb x 64 cb. Optional flag post.
template<int K, int KSPLIT>
__global__ __launch_bounds__(256) void lstm_one(
    const unsigned short* __restrict__ a0, const unsigned short* __restrict__ a1,
    const unsigned short* __restrict__ w,  const float* __restrict__ bias,
    float* __restrict__ c, unsigned short* __restrict__ hout, float* __restrict__ fout,
    unsigned* __restrict__ postbase)
{
  __shared__ __align__(16) unsigned short Bbuf[4][128 * 64];   // 64 KB
  const int tid = threadIdx.x, lane = tid & 63, wv = tid >> 6;
  const int mb = blockIdx.x >> 6, n0h = (blockIdx.x & 63) << 5;
  lstm_step_body<K, KSPLIT>(Bbuf, a0, a1, w, bias, c, hout, fout, tid, lane, wv, mb, n0h);
  if (postbase) publish(postbase + blockIdx.x * 16, 1u);
}

// Fused G step-pairs with DISTRIBUTED RMW-free flags. Grid 256, all resident
// (64KB LDS -> <=2 WG/CU). WGs 0..127 = L1-role (mb,cb); 128..255 = L0-role.
// Step t: L1(t) needs h0 state t+1 + h1 state t; L0(t+1) needs h0 state t+1.
// Flag f0[mb][cb] = (last h0 state written by that L0-WG); f1 likewise for h1.
// One flag certifies BOTH "my h written" AND "my reads done" (posted after the
// whole step). Derived awaits for step t, both roles: f0[mb][*] >= t+1 and
// f1[mb][*] >= t. Write-safety (ping-pong slot occupants' readers) is covered
// by the same two conditions (verified per-slot in the round notes).
// Poll: threads 0..63 each poll one f0 flag, 64..127 one f1 flag (64B lines,
// plain acquire loads, 1 writer per line) -> no RMW, no shared hot line.
__global__ __launch_bounds__(256) void lstm_fusedG(
    const unsigned short* __restrict__ xbf,
    const unsigned short* __restrict__ Wc1, const float* __restrict__ b1,
    const unsigned short* __restrict__ Wc0, const float* __restrict__ b0,
    unsigned short* __restrict__ hb0, unsigned short* __restrict__ hb1,
    float* __restrict__ c1buf, float* __restrict__ c0buf,
    unsigned* __restrict__ flg, int tbase, int G)
{
  __shared__ __align__(16) unsigned short Bbuf[4][128 * 64];   // 64 KB
  const int tid = threadIdx.x, lane = tid & 63, wv = tid >> 6;
  const bool isL1 = blockIdx.x < 128;
  const int W = isL1 ? blockIdx.x : blockIdx.x - 128;
  const int mb = W >> 6, n0h = (W & 63) << 5;
  unsigned* f0 = flg;            // [128] x 16 u32
  unsigned* f1 = flg + 2048;     // [128] x 16 u32
  unsigned* myflag = (isL1 ? f1 : f0) + W * 16;

  for (int g = 0; g < G; ++g) {
    const int t = tbase + g;
    // await (distributed): f0[mb][i] >= t+1, f1[mb][i] >= t
    if (tid < 64) {
      const unsigned* f = f0 + (mb * 64 + tid) * 16;
      while (__hip_atomic_load(f, __ATOMIC_ACQUIRE, __HIP_MEMORY_SCOPE_AGENT)
             < (unsigned)(t + 1))
        __builtin_amdgcn_s_sleep(16);
    } else if (tid < 128) {
      const unsigned* f = f1 + (mb * 64 + (tid - 64)) * 16;
      while (__hip_atomic_load(f, __ATOMIC_ACQUIRE, __HIP_MEMORY_SCOPE_AGENT)
             < (unsigned)t)
        __builtin_amdgcn_s_sleep(16);
    }
    __syncthreads();

    const unsigned short* h0cur = hb0 + (size_t)((t + 1) & 1) * BH;  // state t+1
    if (isL1) {
      // L1(t): reads h0 state t+1 + h1 state t (slot t&1); writes h1 state t+1.
      lstm_step_body<4096, 2048>(Bbuf, h0cur, hb1 + (size_t)(t & 1) * BH,
                                 Wc1, b1, c1buf,
                                 hb1 + (size_t)((t + 1) & 1) * BH, nullptr,
                                 tid, lane, wv, mb, n0h);
      publish(myflag, (unsigned)(t + 1));
    } else {
      // L0(t+1): reads x(t+1) + h0 state t+1; writes h0 state t+2 (slot t&1).
      lstm_step_body<3072, 1024>(Bbuf, xbf + (size_t)(t + 1) * B_SZ * DIN, h0cur,
                                 Wc0, b0, c0buf,
                                 hb0 + (size_t)(t & 1) * BH, nullptr,
                                 tid, lane, wv, mb, n0h);
      publish(myflag, (unsigned)(t + 2));
    }
  }
}

extern "C" void kernel_launch(void* const* d_in, const int* in_sizes, int n_in,
                              void* d_out, int out_size, void* d_ws, size_t ws_size,
                              hipStream_t stream) {
  (void)in_sizes; (void)n_in; (void)out_size; (void)ws_size;
  const float* x    = (const float*)d_in[0];
  const float* h0   = (const float*)d_in[1];
  const float* c0   = (const float*)d_in[2];
  const float* Wih0 = (const float*)d_in[3];
  const float* Whh0 = (const float*)d_in[4];
  const float* b0   = (const float*)d_in[5];
  const float* Wih1 = (const float*)d_in[6];
  const float* Whh1 = (const float*)d_in[7];
  const float* b1   = (const float*)d_in[8];
  float* out = (float*)d_out;

  unsigned short* xbf = (unsigned short*)d_ws;                     // 134 MB
  unsigned short* Wc0 = xbf + (size_t)T_STEPS * B_SZ * DIN;        // 50 MB
  unsigned short* Wc1 = Wc0 + (size_t)NG * 3072;                   // 67 MB
  unsigned short* hb0 = Wc1 + (size_t)NG * 4096;                   // 2*BH
  unsigned short* hb1 = hb0 + 2 * (size_t)BH;                      // 2*BH
  float*          cws = (float*)(hb1 + 2 * (size_t)BH);            // 2*BH fp32
  unsigned*       flg = (unsigned*)(cws + 2 * (size_t)BH);         // 4096 u32

  cvt_x_bf16<<<dim3(4096), dim3(256), 0, stream>>>(
      (const float4*)x, (ushort4*)xbf, T_STEPS * B_SZ * DIN / 4);
  build_wcat<<<dim3(12, NG), dim3(256), 0, stream>>>(Wih0, Whh0, Wc0, DIN, 3072);
  build_wcat<<<dim3(16, NG), dim3(256), 0, stream>>>(Wih1, Whh1, Wc1, H_SZ, 4096);
  init_state<<<dim3(BH / 256), dim3(256), 0, stream>>>(h0, c0, hb0, hb1, cws, flg);

  // State numbering: h0 state s lives in hb0 slot s&1 (h1 likewise).
  // L0(0): reads h0 state 0 (slot 0), writes state 1 (slot 1); posts f0 = 1.
  lstm_one<3072, 1024><<<dim3(128), dim3(256), 0, stream>>>(
      xbf, hb0 + 0, Wc0, b0, cws, hb0 + BH, nullptr, flg);

  // Fused steps t = 0..510 ({L1(t) || L0(t+1)}) in G=16 chunks.
  int t = 0;
  while (t < T_STEPS - 1) {
    int G = (T_STEPS - 1 - t < 16) ? (T_STEPS - 1 - t) : 16;
    lstm_fusedG<<<dim3(256), dim3(256), 0, stream>>>(
        xbf, Wc1, b1, Wc0, b0, hb0, hb1, cws + BH, cws, flg, t, G);
    t += G;
  }

  // L1(511): reads h0 state 512 (slot 0) + h1 state 511 (slot 1); writes out.
  lstm_one<4096, 2048><<<dim3(128), dim3(256), 0, stream>>>(
      hb0 + 0, hb1 + BH, Wc1, b1, cws + BH, hb1 + 0, out, nullptr);
}

// Round 17
// 23996.466 us; speedup vs baseline: 2.9267x; 1.5896x over previous
//
#include <hip/hip_runtime.h>
#include <stdint.h>
#include <stddef.h>

#define T_STEPS 512
#define B_SZ    128
#define DIN     1024
#define H_SZ    2048
#define NG      8192            // 4*H
#define BH      (B_SZ * H_SZ)   // 262144

typedef __attribute__((ext_vector_type(8))) short bf16x8;
typedef __attribute__((ext_vector_type(4))) float f32x4;

static __device__ __forceinline__ unsigned short f2bf(float x) {
  unsigned int u = __float_as_uint(x);
  u += 0x7fffu + ((u >> 16) & 1u);   // RNE; inputs finite
  return (unsigned short)(u >> 16);
}

static __device__ __forceinline__ float sigm(float x) {
  return 1.0f / (1.0f + __expf(-x));
}
static __device__ __forceinline__ float tanh_(float x) {
  float e = __expf(-2.0f * fabsf(x));  // in (0,1], no overflow
  float t = (1.0f - e) / (1.0f + e);
  return x < 0.0f ? -t : t;
}

// global -> LDS async copy, 16B per lane (wave-uniform LDS base).
static __device__ __forceinline__ void async_load16(const void* gsrc, void* ldst) {
  __builtin_amdgcn_global_load_lds(
      (__attribute__((address_space(1))) void*)(const_cast<void*>(gsrc)),
      (__attribute__((address_space(3))) void*)ldst,
      16, 0, 0);
}

// Barrier that memory ops cannot be compiler-moved across (rd4's NaN fix).
static __device__ __forceinline__ void wg_barrier_pinned() {
  __builtin_amdgcn_s_barrier();
  asm volatile("" ::: "memory");
  __builtin_amdgcn_sched_barrier(0);
}

__global__ void cvt_x_bf16(const float4* __restrict__ in, ushort4* __restrict__ out, int n4) {
  int i = blockIdx.x * blockDim.x + threadIdx.x;
  int st = gridDim.x * blockDim.x;
  for (; i < n4; i += st) {
    float4 v = in[i];
    ushort4 o;
    o.x = f2bf(v.x); o.y = f2bf(v.y); o.z = f2bf(v.z); o.w = f2bf(v.w);
    out[i] = o;
  }
}

__global__ void build_wcat(const float* __restrict__ wa, const float* __restrict__ wb,
                           unsigned short* __restrict__ outw, int ka, int K) {
  int k = blockIdx.x * blockDim.x + threadIdx.x;
  int n = blockIdx.y;
  if (k >= K) return;
  int kb = K - ka;
  float v = (k < ka) ? wa[(size_t)n * ka + k]
                     : wb[(size_t)n * kb + (k - ka)];
  outw[(size_t)n * K + k] = f2bf(v);
}

__global__ void init_state(const float* __restrict__ h0, const float* __restrict__ c0,
                           unsigned short* __restrict__ hb0, unsigned short* __restrict__ hb1,
                           float* __restrict__ cws) {
  int i = blockIdx.x * blockDim.x + threadIdx.x;
  if (i < BH) {
    hb0[i] = f2bf(h0[i]);
    hb1[i] = f2bf(h0[BH + i]);
    cws[i] = c0[i];
    cws[BH + i] = c0[BH + i];
  }
}

// One LSTM cell step (rd10 tiling; super-iter pipeline).
// WG tile = 64 rows x 128 gate-cols (32 h-cols). Within a layer: 128 WGs =
// 2 row-blocks (mb) x 64 col-blocks (cb). Wave wv owns rows mb*64+wv*16..+16.
// Lane holds all 4 gates: acc[ct], ct = gate*2 + p -> lane-local epilogue.
// A: direct global->register, 4 named sets, refilled 4 ahead.
// B: LDS ring of EIGHT 16KB buffers. Super-iteration of 4 k-tiles:
//   [vmcnt(8) -> barrier -> stage iters +4..+7 (16 chunks) -> 4 iters of
//    ds_read+MFMA+A-refill, NO per-iter wait/barrier]
// In-order FIFO: at each boundary a wave's outstanding = 16 stage-chunks +
// 8 A-refills; vmcnt(8) retires all its stage-chunks for the buffers read
// this super (uniform at prologue/steady/tail since KT % 4 == 0). Stages
// issued after the barrier write slots (M+4..M+7)&7 — the complement of the
// slots (M..M+3)&7 being read (M % 8 in {0,4}).
template<int K, int KSPLIT>
static __device__ __forceinline__ void lstm_step_body(
    unsigned short (*Bbuf)[128 * 64],
    const unsigned short* __restrict__ a0,   // [128][KSPLIT] row-major
    const unsigned short* __restrict__ a1,   // [128][H_SZ] row-major
    const unsigned short* __restrict__ w,    // [NG][K] bf16
    const float* __restrict__ bias,          // [NG] fp32
    float* __restrict__ c,                   // [B][H] fp32, in-place (tile-private)
    unsigned short* __restrict__ hout,       // [B][H] bf16
    float* __restrict__ fout,                // optional [B][H] fp32
    int tid, int lane, int wv, int mb, int n0h)
{
  constexpr int KT = K >> 6;   // 48 or 64, divisible by 4
  f32x4 acc[8] = {};

  const int arow = mb * 64 + wv * 16 + (lane & 15);
  const unsigned short* r0p = a0 + (size_t)arow * KSPLIT;
  const unsigned short* r1p = a1 + (size_t)arow * H_SZ;
  const int klo = (lane >> 4) << 3;   // lane-group k offset (elems)

  auto loadA = [&](int kt, bf16x8 (&A)[2]) {
    const int kb = kt << 6;
    const bool sA = kb < KSPLIT;     // tiles never straddle (KSPLIT % 64 == 0)
    const unsigned short* bp = (sA ? r0p : r1p) + (sA ? kb : kb - KSPLIT) + klo;
    A[0] = *(const bf16x8*)(bp);
    A[1] = *(const bf16x8*)(bp + 32);
  };

  // B-tile 128 gate-rows x 64 k = 16KB = 1024 x 16B chunks; 4 per thread.
  auto stageB = [&](int kt) {
    const int kb = kt << 6;
#pragma unroll
    for (int it = 0; it < 4; ++it) {
      int cid = it * 256 + tid;
      int nl  = cid >> 3;                            // gate-row 0..127
      int chs = (cid & 7) ^ (nl & 7);                // pre-swizzled source chunk
      int nn  = ((nl >> 5) << 11) + n0h + (nl & 31);
      const unsigned short* src = w + (size_t)nn * K + kb + (chs << 3);
      async_load16(src, &Bbuf[kt & 7][(it * 256 + wv * 64) * 8]);
    }
  };

  // One k-tile: pure compute + A-refill (no waits/barriers inside).
  auto iter = [&](int kt, bf16x8 (&A)[2]) {
    const int bq = kt & 7;
#pragma unroll
    for (int kkk = 0; kkk < 2; ++kkk) {
      const int ch = kkk * 4 + (lane >> 4);
      const int cswz = (ch ^ (lane & 7)) << 3;       // (nl&7) == lane&7 for all ct
      bf16x8 bfr[8];
#pragma unroll
      for (int ct = 0; ct < 8; ++ct)
        bfr[ct] = *(const bf16x8*)&Bbuf[bq][(ct * 16 + (lane & 15)) * 64 + cswz];
#pragma unroll
      for (int ct = 0; ct < 8; ++ct)
        acc[ct] = __builtin_amdgcn_mfma_f32_16x16x32_bf16(A[kkk], bfr[ct], acc[ct], 0, 0, 0);
    }
    if (kt + 4 < KT) loadA(kt + 4, A);               // refill own named set post-use
  };

  // Entry guard: counts below assume an empty vmcnt FIFO.
  asm volatile("s_waitcnt vmcnt(0)" ::: "memory");

  bf16x8 A0[2], A1[2], A2[2], A3[2];
  // Prologue: stage iters 0..3 (16 chunks) + load A0..A3 (8 ops).
  stageB(0); stageB(1); stageB(2); stageB(3);
  loadA(0, A0); loadA(1, A1); loadA(2, A2); loadA(3, A3);

  for (int m = 0; m < KT; m += 4) {
    // Boundary: retire own stage-chunks for buffers m..m+3 (the 8 newest ops
    // are A-refills; everything older — incl. all 16 stage-chunks — drains).
    asm volatile("s_waitcnt vmcnt(8)" ::: "memory");
    wg_barrier_pinned();
    if (m + 4 < KT) { stageB(m + 4); stageB(m + 5); stageB(m + 6); stageB(m + 7); }
    iter(m,     A0);
    iter(m + 1, A1);
    iter(m + 2, A2);
    iter(m + 3, A3);
  }

  // Epilogue (lane-local; rd10-verified). C/D map: col(nl)=lane&15 ->
  // nl = ct*16+(lane&15); gate = ct>>1; hcol = n0h + (ct&1)*16 + (lane&15).
#pragma unroll
  for (int p = 0; p < 2; ++p) {
    const int hc = n0h + p * 16 + (lane & 15);
    const float bi  = bias[hc];
    const float bff = bias[H_SZ + hc];
    const float bg  = bias[2 * H_SZ + hc];
    const float bo  = bias[3 * H_SZ + hc];
#pragma unroll
    for (int r = 0; r < 4; ++r) {
      int row = mb * 64 + wv * 16 + ((lane >> 4) << 2) + r;
      size_t idx = (size_t)row * H_SZ + hc;
      float iv = sigm(acc[p    ][r] + bi);
      float fv = sigm(acc[p + 2][r] + bff);
      float gv = tanh_(acc[p + 4][r] + bg);
      float ov = sigm(acc[p + 6][r] + bo);
      float cn = fv * c[idx] + iv * gv;
      c[idx] = cn;
      float hn = ov * tanh_(cn);
      hout[idx] = f2bf(hn);
      if (fout) fout[idx] = hn;
    }
  }
}

// Single step (schedule edges). Grid 128 = 2 mb x 64 cb.
template<int K, int KSPLIT>
__global__ __launch_bounds__(256) void lstm_one(
    const unsigned short* __restrict__ a0, const unsigned short* __restrict__ a1,
    const unsigned short* __restrict__ w,  const float* __restrict__ bias,
    float* __restrict__ c, unsigned short* __restrict__ hout, float* __restrict__ fout)
{
  __shared__ __align__(16) unsigned short Bbuf[8][128 * 64];   // 128 KB
  const int tid = threadIdx.x, lane = tid & 63, wv = tid >> 6;
  const int mb = blockIdx.x >> 6, n0h = (blockIdx.x & 63) << 5;
  lstm_step_body<K, KSPLIT>(Bbuf, a0, a1, w, bias, c, hout, fout, tid, lane, wv, mb, n0h);
}

// Layer-split pair: grid 256. WGs 0..127 run L1(t), WGs 128..255 run L0(t+1)
// CONCURRENTLY (independent: both read only buffers published at the
// preceding dispatch boundary; writes are disjoint and read only after the
// next boundary). Wall per pair = max(L1, L0) instead of L1 + L0.
template<int K1, int KS1, int K2, int KS2>
__global__ __launch_bounds__(256) void lstm_pair(
    const unsigned short* __restrict__ a0_1, const unsigned short* __restrict__ a1_1,
    const unsigned short* __restrict__ w1,   const float* __restrict__ bias1,
    float* __restrict__ c1, unsigned short* __restrict__ h1out,
    const unsigned short* __restrict__ a0_2, const unsigned short* __restrict__ a1_2,
    const unsigned short* __restrict__ w2,   const float* __restrict__ bias2,
    float* __restrict__ c2, unsigned short* __restrict__ h2out)
{
  __shared__ __align__(16) unsigned short Bbuf[8][128 * 64];   // 128 KB
  const int tid = threadIdx.x, lane = tid & 63, wv = tid >> 6;
  if (blockIdx.x < 128) {
    const int mb = blockIdx.x >> 6, n0h = (blockIdx.x & 63) << 5;
    lstm_step_body<K1, KS1>(Bbuf, a0_1, a1_1, w1, bias1, c1, h1out, nullptr, tid, lane, wv, mb, n0h);
  } else {
    const int W = blockIdx.x - 128;
    const int mb = W >> 6, n0h = (W & 63) << 5;
    lstm_step_body<K2, KS2>(Bbuf, a0_2, a1_2, w2, bias2, c2, h2out, nullptr, tid, lane, wv, mb, n0h);
  }
}

extern "C" void kernel_launch(void* const* d_in, const int* in_sizes, int n_in,
                              void* d_out, int out_size, void* d_ws, size_t ws_size,
                              hipStream_t stream) {
  (void)in_sizes; (void)n_in; (void)out_size; (void)ws_size;
  const float* x    = (const float*)d_in[0];
  const float* h0   = (const float*)d_in[1];
  const float* c0   = (const float*)d_in[2];
  const float* Wih0 = (const float*)d_in[3];
  const float* Whh0 = (const float*)d_in[4];
  const float* b0   = (const float*)d_in[5];
  const float* Wih1 = (const float*)d_in[6];
  const float* Whh1 = (const float*)d_in[7];
  const float* b1   = (const float*)d_in[8];
  float* out = (float*)d_out;

  unsigned short* xbf = (unsigned short*)d_ws;                     // 134 MB
  unsigned short* Wc0 = xbf + (size_t)T_STEPS * B_SZ * DIN;        // 50 MB
  unsigned short* Wc1 = Wc0 + (size_t)NG * 3072;                   // 67 MB
  unsigned short* hb0 = Wc1 + (size_t)NG * 4096;                   // 2 * BH (ping-pong)
  unsigned short* hb1 = hb0 + 2 * (size_t)BH;                      // 2 * BH
  float*          cws = (float*)(hb1 + 2 * (size_t)BH);            // 2 * BH fp32

  cvt_x_bf16<<<dim3(4096), dim3(256), 0, stream>>>(
      (const float4*)x, (ushort4*)xbf, T_STEPS * B_SZ * DIN / 4);
  build_wcat<<<dim3(12, NG), dim3(256), 0, stream>>>(Wih0, Whh0, Wc0, DIN, 3072);
  build_wcat<<<dim3(16, NG), dim3(256), 0, stream>>>(Wih1, Whh1, Wc1, H_SZ, 4096);
  init_state<<<dim3(BH / 256), dim3(256), 0, stream>>>(h0, c0, hb0, hb1, cws);

  // Schedule: L0(0); { L1(t) || L0(t+1) } t=0..510; L1(511)->out.
  // h slots: L0(t) reads hb0 slot[t&1], writes slot[(t+1)&1];
  //          L1(t) reads hb0 slot[(t+1)&1] + hb1 slot[t&1], writes hb1 slot[(t+1)&1].
  lstm_one<3072, 1024><<<dim3(128), dim3(256), 0, stream>>>(
      xbf, hb0 + 0, Wc0, b0, cws, hb0 + BH, nullptr);

  for (int t = 0; t < T_STEPS - 1; ++t) {
    const unsigned short* h0cur = hb0 + (size_t)((t + 1) & 1) * BH;
    lstm_pair<4096, 2048, 3072, 1024><<<dim3(256), dim3(256), 0, stream>>>(
        /*L1(t)*/   h0cur, hb1 + (size_t)(t & 1) * BH, Wc1, b1,
                    cws + BH, hb1 + (size_t)((t + 1) & 1) * BH,
        /*L0(t+1)*/ xbf + (size_t)(t + 1) * B_SZ * DIN, h0cur, Wc0, b0,
                    cws, hb0 + (size_t)(t & 1) * BH);
  }
  // L1(511): reads hb0 slot0, hb1 slot1; writes hb1 slot0 + fp32 out.
  lstm_one<4096, 2048><<<dim3(128), dim3(256), 0, stream>>>(
      hb0 + 0, hb1 + BH, Wc1, b1, cws + BH, hb1 + 0, out);
}

// Round 18
// 22375.824 us; speedup vs baseline: 3.1387x; 1.0724x over previous
//
#include <hip/hip_runtime.h>
#include <stdint.h>
#include <stddef.h>

#define T_STEPS 512
#define B_SZ    128
#define DIN     1024
#define H_SZ    2048
#define NG      8192            // 4*H
#define BH      (B_SZ * H_SZ)   // 262144

typedef __attribute__((ext_vector_type(8))) short bf16x8;
typedef __attribute__((ext_vector_type(4))) float f32x4;

static __device__ __forceinline__ unsigned short f2bf(float x) {
  unsigned int u = __float_as_uint(x);
  u += 0x7fffu + ((u >> 16) & 1u);   // RNE; inputs finite
  return (unsigned short)(u >> 16);
}

static __device__ __forceinline__ float sigm(float x) {
  return 1.0f / (1.0f + __expf(-x));
}
static __device__ __forceinline__ float tanh_(float x) {
  float e = __expf(-2.0f * fabsf(x));  // in (0,1], no overflow
  float t = (1.0f - e) / (1.0f + e);
  return x < 0.0f ? -t : t;
}

// global -> LDS async copy, 16B per lane (wave-uniform LDS base).
static __device__ __forceinline__ void async_load16(const void* gsrc, void* ldst) {
  __builtin_amdgcn_global_load_lds(
      (__attribute__((address_space(1))) void*)(const_cast<void*>(gsrc)),
      (__attribute__((address_space(3))) void*)ldst,
      16, 0, 0);
}

// Barrier that memory ops cannot be compiler-moved across (rd4's NaN fix).
static __device__ __forceinline__ void wg_barrier_pinned() {
  __builtin_amdgcn_s_barrier();
  asm volatile("" ::: "memory");
  __builtin_amdgcn_sched_barrier(0);
}

__global__ void cvt_x_bf16(const float4* __restrict__ in, ushort4* __restrict__ out, int n4) {
  int i = blockIdx.x * blockDim.x + threadIdx.x;
  int st = gridDim.x * blockDim.x;
  for (; i < n4; i += st) {
    float4 v = in[i];
    ushort4 o;
    o.x = f2bf(v.x); o.y = f2bf(v.y); o.z = f2bf(v.z); o.w = f2bf(v.w);
    out[i] = o;
  }
}

__global__ void build_wcat(const float* __restrict__ wa, const float* __restrict__ wb,
                           unsigned short* __restrict__ outw, int ka, int K) {
  int k = blockIdx.x * blockDim.x + threadIdx.x;
  int n = blockIdx.y;
  if (k >= K) return;
  int kb = K - ka;
  float v = (k < ka) ? wa[(size_t)n * ka + k]
                     : wb[(size_t)n * kb + (k - ka)];
  outw[(size_t)n * K + k] = f2bf(v);
}

__global__ void init_state(const float* __restrict__ h0, const float* __restrict__ c0,
                           unsigned short* __restrict__ hb0, unsigned short* __restrict__ hb1,
                           float* __restrict__ cws) {
  int i = blockIdx.x * blockDim.x + threadIdx.x;
  if (i < BH) {
    hb0[i] = f2bf(h0[i]);
    hb1[i] = f2bf(h0[BH + i]);
    cws[i] = c0[i];
    cws[BH + i] = c0[BH + i];
  }
}

// One LSTM cell step (rd10 body; ONLY change: B prefetch depth 3 -> 7).
// WG tile = 64 rows x 128 gate-cols (32 h-cols). Within a layer: 128 WGs =
// 2 row-blocks (mb) x 64 col-blocks (cb). Wave wv owns rows mb*64+wv*16..+16.
// Lane holds all 4 gates: acc[ct], ct = gate*2 + p -> lane-local epilogue.
// A: direct global->register, 4 named sets, 4-ahead.
// B: LDS ring of EIGHT 16KB buffers, staged 7 ahead via global_load_lds,
// XOR-swizzled. Per-wave VMEM per iter: 4 stageB chunks + 2 loadA.
// Per-iter fine ladder (rd10 cadence — rd17's coarse cadence convoyed):
// retire own B(kt+1) before the barrier. In-order FIFO, ops issued after
// B(kt+1)'s chunks: SB(kt+2..kt+7) valid ones x4 + LA(kt-2..kt+4) valid x2.
// steady(rem>=7)=38, rem=6:34, 5:30, 4:26, 3:20, 2:14, 1:8, 0: none.
template<int K, int KSPLIT>
static __device__ __forceinline__ void lstm_step_body(
    unsigned short (*Bbuf)[128 * 64],
    const unsigned short* __restrict__ a0,   // [128][KSPLIT] row-major
    const unsigned short* __restrict__ a1,   // [128][H_SZ] row-major
    const unsigned short* __restrict__ w,    // [NG][K] bf16
    const float* __restrict__ bias,          // [NG] fp32
    float* __restrict__ c,                   // [B][H] fp32, in-place (tile-private)
    unsigned short* __restrict__ hout,       // [B][H] bf16
    float* __restrict__ fout,                // optional [B][H] fp32
    int tid, int lane, int wv, int mb, int n0h)
{
  constexpr int KT = K >> 6;   // 48 or 64, divisible by 4
  f32x4 acc[8] = {};

  const int arow = mb * 64 + wv * 16 + (lane & 15);
  const unsigned short* r0p = a0 + (size_t)arow * KSPLIT;
  const unsigned short* r1p = a1 + (size_t)arow * H_SZ;
  const int klo = (lane >> 4) << 3;   // lane-group k offset (elems)

  auto loadA = [&](int kt, bf16x8 (&A)[2]) {
    const int kb = kt << 6;
    const bool sA = kb < KSPLIT;     // tiles never straddle (KSPLIT % 64 == 0)
    const unsigned short* bp = (sA ? r0p : r1p) + (sA ? kb : kb - KSPLIT) + klo;
    A[0] = *(const bf16x8*)(bp);
    A[1] = *(const bf16x8*)(bp + 32);
  };

  // B-tile 128 gate-rows x 64 k = 16KB = 1024 x 16B chunks; 4 per thread.
  auto stageB = [&](int kt) {
    const int kb = kt << 6;
#pragma unroll
    for (int it = 0; it < 4; ++it) {
      int cid = it * 256 + tid;
      int nl  = cid >> 3;                            // gate-row 0..127
      int chs = (cid & 7) ^ (nl & 7);                // pre-swizzled source chunk
      int nn  = ((nl >> 5) << 11) + n0h + (nl & 31);
      const unsigned short* src = w + (size_t)nn * K + kb + (chs << 3);
      async_load16(src, &Bbuf[kt & 7][(it * 256 + wv * 64) * 8]);
    }
  };

  auto iter = [&](int kt, bf16x8 (&A)[2]) {
    if (kt + 7 < KT) stageB(kt + 7);                 // issue stage early (depth 7)
    const int bq = kt & 7;
#pragma unroll
    for (int kkk = 0; kkk < 2; ++kkk) {
      const int ch = kkk * 4 + (lane >> 4);
      const int cswz = (ch ^ (lane & 7)) << 3;       // (nl&7) == lane&7 for all ct
      bf16x8 bfr[8];
#pragma unroll
      for (int ct = 0; ct < 8; ++ct)
        bfr[ct] = *(const bf16x8*)&Bbuf[bq][(ct * 16 + (lane & 15)) * 64 + cswz];
#pragma unroll
      for (int ct = 0; ct < 8; ++ct)
        acc[ct] = __builtin_amdgcn_mfma_f32_16x16x32_bf16(A[kkk], bfr[ct], acc[ct], 0, 0, 0);
    }
    if (kt + 4 < KT) loadA(kt + 4, A);               // refill own named set post-use
    int rem = KT - 1 - kt;
    if (rem >= 7)      asm volatile("s_waitcnt vmcnt(38)" ::: "memory");
    else if (rem == 6) asm volatile("s_waitcnt vmcnt(34)" ::: "memory");
    else if (rem == 5) asm volatile("s_waitcnt vmcnt(30)" ::: "memory");
    else if (rem == 4) asm volatile("s_waitcnt vmcnt(26)" ::: "memory");
    else if (rem == 3) asm volatile("s_waitcnt vmcnt(20)" ::: "memory");
    else if (rem == 2) asm volatile("s_waitcnt vmcnt(14)" ::: "memory");
    else if (rem == 1) asm volatile("s_waitcnt vmcnt(8)"  ::: "memory");
    wg_barrier_pinned();   // rem==0: barrier only (protects next-body Bbuf reuse)
  };

  // Entry guard: prologue counts assume an empty vmcnt FIFO.
  asm volatile("s_waitcnt vmcnt(0)" ::: "memory");

  bf16x8 A0[2], A1[2], A2[2], A3[2];
  // Prologue: SB0,LA0,SB1,LA1,SB2,LA2,SB3,LA3,SB4,SB5,SB6 = 28 chunks + 8 LA.
  // Retire B0: ops after B0's 4 chunks = 8 LA + 24 SB = 32.
  stageB(0); loadA(0, A0);
  stageB(1); loadA(1, A1);
  stageB(2); loadA(2, A2);
  stageB(3); loadA(3, A3);
  stageB(4); stageB(5); stageB(6);
  asm volatile("s_waitcnt vmcnt(32)" ::: "memory");
  wg_barrier_pinned();

  for (int kt = 0; kt < KT; kt += 4) {
    iter(kt,     A0);
    iter(kt + 1, A1);
    iter(kt + 2, A2);
    iter(kt + 3, A3);
  }

  // Epilogue (lane-local; rd10-verified). C/D map: col(nl)=lane&15 ->
  // nl = ct*16+(lane&15); gate = ct>>1; hcol = n0h + (ct&1)*16 + (lane&15).
#pragma unroll
  for (int p = 0; p < 2; ++p) {
    const int hc = n0h + p * 16 + (lane & 15);
    const float bi  = bias[hc];
    const float bff = bias[H_SZ + hc];
    const float bg  = bias[2 * H_SZ + hc];
    const float bo  = bias[3 * H_SZ + hc];
#pragma unroll
    for (int r = 0; r < 4; ++r) {
      int row = mb * 64 + wv * 16 + ((lane >> 4) << 2) + r;
      size_t idx = (size_t)row * H_SZ + hc;
      float iv = sigm(acc[p    ][r] + bi);
      float fv = sigm(acc[p + 2][r] + bff);
      float gv = tanh_(acc[p + 4][r] + bg);
      float ov = sigm(acc[p + 6][r] + bo);
      float cn = fv * c[idx] + iv * gv;
      c[idx] = cn;
      float hn = ov * tanh_(cn);
      hout[idx] = f2bf(hn);
      if (fout) fout[idx] = hn;
    }
  }
}

// Single step (schedule edges). Grid 128 = 2 mb x 64 cb.
template<int K, int KSPLIT>
__global__ __launch_bounds__(256) void lstm_one(
    const unsigned short* __restrict__ a0, const unsigned short* __restrict__ a1,
    const unsigned short* __restrict__ w,  const float* __restrict__ bias,
    float* __restrict__ c, unsigned short* __restrict__ hout, float* __restrict__ fout)
{
  __shared__ __align__(16) unsigned short Bbuf[8][128 * 64];   // 128 KB
  const int tid = threadIdx.x, lane = tid & 63, wv = tid >> 6;
  const int mb = blockIdx.x >> 6, n0h = (blockIdx.x & 63) << 5;
  lstm_step_body<K, KSPLIT>(Bbuf, a0, a1, w, bias, c, hout, fout, tid, lane, wv, mb, n0h);
}

// Layer-split pair: grid 256. WGs 0..127 run L1(t), WGs 128..255 run L0(t+1)
// CONCURRENTLY (independent: both read only buffers published at the
// preceding dispatch boundary; writes are disjoint and read only after the
// next boundary). Wall per pair = max(L1, L0) instead of L1 + L0.
template<int K1, int KS1, int K2, int KS2>
__global__ __launch_bounds__(256) void lstm_pair(
    const unsigned short* __restrict__ a0_1, const unsigned short* __restrict__ a1_1,
    const unsigned short* __restrict__ w1,   const float* __restrict__ bias1,
    float* __restrict__ c1, unsigned short* __restrict__ h1out,
    const unsigned short* __restrict__ a0_2, const unsigned short* __restrict__ a1_2,
    const unsigned short* __restrict__ w2,   const float* __restrict__ bias2,
    float* __restrict__ c2, unsigned short* __restrict__ h2out)
{
  __shared__ __align__(16) unsigned short Bbuf[8][128 * 64];   // 128 KB
  const int tid = threadIdx.x, lane = tid & 63, wv = tid >> 6;
  if (blockIdx.x < 128) {
    const int mb = blockIdx.x >> 6, n0h = (blockIdx.x & 63) << 5;
    lstm_step_body<K1, KS1>(Bbuf, a0_1, a1_1, w1, bias1, c1, h1out, nullptr, tid, lane, wv, mb, n0h);
  } else {
    const int W = blockIdx.x - 128;
    const int mb = W >> 6, n0h = (W & 63) << 5;
    lstm_step_body<K2, KS2>(Bbuf, a0_2, a1_2, w2, bias2, c2, h2out, nullptr, tid, lane, wv, mb, n0h);
  }
}

extern "C" void kernel_launch(void* const* d_in, const int* in_sizes, int n_in,
                              void* d_out, int out_size, void* d_ws, size_t ws_size,
                              hipStream_t stream) {
  (void)in_sizes; (void)n_in; (void)out_size; (void)ws_size;
  const float* x    = (const float*)d_in[0];
  const float* h0   = (const float*)d_in[1];
  const float* c0   = (const float*)d_in[2];
  const float* Wih0 = (const float*)d_in[3];
  const float* Whh0 = (const float*)d_in[4];
  const float* b0   = (const float*)d_in[5];
  const float* Wih1 = (const float*)d_in[6];
  const float* Whh1 = (const float*)d_in[7];
  const float* b1   = (const float*)d_in[8];
  float* out = (float*)d_out;

  unsigned short* xbf = (unsigned short*)d_ws;                     // 134 MB
  unsigned short* Wc0 = xbf + (size_t)T_STEPS * B_SZ * DIN;        // 50 MB
  unsigned short* Wc1 = Wc0 + (size_t)NG * 3072;                   // 67 MB
  unsigned short* hb0 = Wc1 + (size_t)NG * 4096;                   // 2 * BH (ping-pong)
  unsigned short* hb1 = hb0 + 2 * (size_t)BH;                      // 2 * BH
  float*          cws = (float*)(hb1 + 2 * (size_t)BH);            // 2 * BH fp32

  cvt_x_bf16<<<dim3(4096), dim3(256), 0, stream>>>(
      (const float4*)x, (ushort4*)xbf, T_STEPS * B_SZ * DIN / 4);
  build_wcat<<<dim3(12, NG), dim3(256), 0, stream>>>(Wih0, Whh0, Wc0, DIN, 3072);
  build_wcat<<<dim3(16, NG), dim3(256), 0, stream>>>(Wih1, Whh1, Wc1, H_SZ, 4096);
  init_state<<<dim3(BH / 256), dim3(256), 0, stream>>>(h0, c0, hb0, hb1, cws);

  // Schedule: L0(0); { L1(t) || L0(t+1) } t=0..510; L1(511)->out.
  // h slots: L0(t) reads hb0 slot[t&1], writes slot[(t+1)&1];
  //          L1(t) reads hb0 slot[(t+1)&1] + hb1 slot[t&1], writes hb1 slot[(t+1)&1].
  lstm_one<3072, 1024><<<dim3(128), dim3(256), 0, stream>>>(
      xbf, hb0 + 0, Wc0, b0, cws, hb0 + BH, nullptr);

  for (int t = 0; t < T_STEPS - 1; ++t) {
    const unsigned short* h0cur = hb0 + (size_t)((t + 1) & 1) * BH;
    lstm_pair<4096, 2048, 3072, 1024><<<dim3(256), dim3(256), 0, stream>>>(
        /*L1(t)*/   h0cur, hb1 + (size_t)(t & 1) * BH, Wc1, b1,
                    cws + BH, hb1 + (size_t)((t + 1) & 1) * BH,
        /*L0(t+1)*/ xbf + (size_t)(t + 1) * B_SZ * DIN, h0cur, Wc0, b0,
                    cws, hb0 + (size_t)(t & 1) * BH);
  }
  // L1(511): reads hb0 slot0, hb1 slot1; writes hb1 slot0 + fp32 out.
  lstm_one<4096, 2048><<<dim3(128), dim3(256), 0, stream>>>(
      hb0 + 0, hb1 + BH, Wc1, b1, cws + BH, hb1 + 0, out);
}